// Round 1
// baseline (1620.493 us; speedup 1.0000x reference)
//
#include <hip/hip_runtime.h>
#include <hip/hip_bf16.h>
#include <math.h>

#define NN 100000
#define NE 625000
#define DIN 128
#define DH 256

// ---------------------------------------------------------------------------
// Phase 1: edge scatter. 32 threads per edge, each thread handles 4 floats.
// agg[dst] += x[src]; cnt[dst] += 1.
// ---------------------------------------------------------------------------
__global__ __launch_bounds__(256)
void sage_scatter(const float* __restrict__ x,
                  const int* __restrict__ ei,
                  float* __restrict__ agg,
                  float* __restrict__ cnt) {
    int gid = blockIdx.x * 256 + threadIdx.x;
    int e = gid >> 5;
    if (e >= NE) return;
    int lane = gid & 31;
    int src = ei[e];
    int dst = ei[NE + e];
    float4 v = *reinterpret_cast<const float4*>(x + (size_t)src * DIN + lane * 4);
    float* a = agg + (size_t)dst * DIN + lane * 4;
    unsafeAtomicAdd(a + 0, v.x);
    unsafeAtomicAdd(a + 1, v.y);
    unsafeAtomicAdd(a + 2, v.z);
    unsafeAtomicAdd(a + 3, v.w);
    if (lane == 0) unsafeAtomicAdd(cnt + dst, 1.0f);
}

// ---------------------------------------------------------------------------
// Phase 2: fused GEMM + heads + log_softmax.
// h = [mean | x] @ [w_l ; w_r] + b_l, relu  (K=256, N=256)
// pr = h@w_p+b_p (7), sv = h@w_s+b_s (6), log_softmax each.
// Block: 256 threads, BM=64 nodes, BN=256 (full), BK=32.
// Thread computes 16 nodes x 4 cols in registers.
// ---------------------------------------------------------------------------
__global__ __launch_bounds__(256, 2)
void sage_gemm(const float* __restrict__ x,
               const float* __restrict__ agg,
               const float* __restrict__ cnt,
               const float* __restrict__ w_l,
               const float* __restrict__ b_l,
               const float* __restrict__ w_r,
               const float* __restrict__ w_p,
               const float* __restrict__ b_p,
               const float* __restrict__ w_s,
               const float* __restrict__ b_s,
               float* __restrict__ out) {
    __shared__ float smem[17408];          // 69632 B: As(8K)+Ws(32K) / h tile (66560 B)
    __shared__ float out13[64][13];
    float* As = smem;                      // [32][64]  As[k][m]
    float* Ws = smem + 2048;               // [32][256] Ws[k][c]

    const int t = threadIdx.x;
    const int node0 = blockIdx.x * 64;

    float acc[16][4];
#pragma unroll
    for (int i = 0; i < 16; ++i)
#pragma unroll
        for (int j = 0; j < 4; ++j) acc[i][j] = 0.f;

    const int c0 = (t & 63) * 4;           // output cols c0..c0+3
    const int m0 = (t >> 6) * 16;          // output rows m0..m0+15 (wave-uniform)

    // staging mapping: thread loads 8 consecutive k for one node
    const int node_l = t >> 2;             // 0..63
    const int kseg = (t & 3) * 8;          // 0,8,16,24
    const int gnode_s = node0 + node_l;
    const bool valid_s = gnode_s < NN;
    float inv = 0.f;
    if (valid_s) inv = 1.f / fmaxf(cnt[gnode_s], 1.f);

    float av[8];
    float4 wv[8];

    // ---- chunk loader (global -> registers) ----
    auto loadA = [&](int kc, float a[8]) {
        const int kk = kc * 32 + kseg;
        if (valid_s) {
            const float* srcp = (kk < 128) ? (agg + (size_t)gnode_s * DIN + kk)
                                           : (x + (size_t)gnode_s * DIN + (kk - 128));
            float4 u0 = reinterpret_cast<const float4*>(srcp)[0];
            float4 u1 = reinterpret_cast<const float4*>(srcp)[1];
            float s = (kk < 128) ? inv : 1.f;
            a[0] = u0.x * s; a[1] = u0.y * s; a[2] = u0.z * s; a[3] = u0.w * s;
            a[4] = u1.x * s; a[5] = u1.y * s; a[6] = u1.z * s; a[7] = u1.w * s;
        } else {
#pragma unroll
            for (int j = 0; j < 8; ++j) a[j] = 0.f;
        }
    };
    auto loadW = [&](int kc, float4 w[8]) {
        const float* wsrc = (kc < 4) ? (w_l + (size_t)kc * 32 * 256)
                                     : (w_r + (size_t)(kc - 4) * 32 * 256);
#pragma unroll
        for (int j = 0; j < 8; ++j)
            w[j] = reinterpret_cast<const float4*>(wsrc)[t + j * 256];
    };

    loadA(0, av);
    loadW(0, wv);

    for (int kc = 0; kc < 8; ++kc) {
        __syncthreads();   // previous compute done reading LDS
#pragma unroll
        for (int j = 0; j < 8; ++j) As[(kseg + j) * 64 + node_l] = av[j];
#pragma unroll
        for (int j = 0; j < 8; ++j) reinterpret_cast<float4*>(Ws)[t + j * 256] = wv[j];
        __syncthreads();

        // prefetch next chunk (overlaps with compute below)
        float avn[8];
        float4 wvn[8];
        if (kc < 7) { loadA(kc + 1, avn); loadW(kc + 1, wvn); }

#pragma unroll 4
        for (int k = 0; k < 32; ++k) {
            float4 w = *reinterpret_cast<const float4*>(Ws + k * 256 + c0);
            const float* ap = As + k * 64 + m0;
            float4 aa[4];
            aa[0] = reinterpret_cast<const float4*>(ap)[0];
            aa[1] = reinterpret_cast<const float4*>(ap)[1];
            aa[2] = reinterpret_cast<const float4*>(ap)[2];
            aa[3] = reinterpret_cast<const float4*>(ap)[3];
#pragma unroll
            for (int g = 0; g < 4; ++g) {
                float a4[4] = {aa[g].x, aa[g].y, aa[g].z, aa[g].w};
#pragma unroll
                for (int q = 0; q < 4; ++q) {
                    const int i = g * 4 + q;
                    acc[i][0] += a4[q] * w.x;
                    acc[i][1] += a4[q] * w.y;
                    acc[i][2] += a4[q] * w.z;
                    acc[i][3] += a4[q] * w.w;
                }
            }
        }

        if (kc < 7) {
#pragma unroll
            for (int j = 0; j < 8; ++j) { av[j] = avn[j]; wv[j] = wvn[j]; }
        }
    }

    // ---- epilogue: h tile -> LDS (stride 260 to dodge bank conflicts) ----
    __syncthreads();
    float4 bl = *reinterpret_cast<const float4*>(b_l + c0);
#pragma unroll
    for (int i = 0; i < 16; ++i) {
        float4 hv;
        hv.x = fmaxf(acc[i][0] + bl.x, 0.f);
        hv.y = fmaxf(acc[i][1] + bl.y, 0.f);
        hv.z = fmaxf(acc[i][2] + bl.z, 0.f);
        hv.w = fmaxf(acc[i][3] + bl.w, 0.f);
        *reinterpret_cast<float4*>(smem + (size_t)(m0 + i) * 260 + c0) = hv;
    }
    __syncthreads();

    // ---- heads: 64 nodes x 13 outputs = 832 dots of length 256 ----
    for (int idx = t; idx < 832; idx += 256) {
        const int m = idx / 13;            // lanes share m in groups of 13 -> LDS broadcast
        const int o = idx % 13;
        const float* hrow = smem + (size_t)m * 260;
        float s = 0.f;
        if (o < 7) {
            for (int k = 0; k < 256; k += 4) {
                float4 hv = *reinterpret_cast<const float4*>(hrow + k);
                s += hv.x * w_p[k * 7 + o] + hv.y * w_p[(k + 1) * 7 + o]
                   + hv.z * w_p[(k + 2) * 7 + o] + hv.w * w_p[(k + 3) * 7 + o];
            }
            s += b_p[o];
        } else {
            const int oo = o - 7;
            for (int k = 0; k < 256; k += 4) {
                float4 hv = *reinterpret_cast<const float4*>(hrow + k);
                s += hv.x * w_s[k * 6 + oo] + hv.y * w_s[(k + 1) * 6 + oo]
                   + hv.z * w_s[(k + 2) * 6 + oo] + hv.w * w_s[(k + 3) * 6 + oo];
            }
            s += b_s[oo];
        }
        out13[m][o] = s;
    }
    __syncthreads();

    // ---- log_softmax + write ----
    if (t < 64) {
        const int gnode = node0 + t;
        if (gnode < NN) {
            float v[7], mx = -1e30f;
#pragma unroll
            for (int j = 0; j < 7; ++j) { v[j] = out13[t][j]; mx = fmaxf(mx, v[j]); }
            float sum = 0.f;
#pragma unroll
            for (int j = 0; j < 7; ++j) sum += expf(v[j] - mx);
            const float lse = mx + logf(sum);
#pragma unroll
            for (int j = 0; j < 7; ++j) out[(size_t)gnode * 7 + j] = v[j] - lse;

            float u[6], mx2 = -1e30f;
#pragma unroll
            for (int j = 0; j < 6; ++j) { u[j] = out13[t][7 + j]; mx2 = fmaxf(mx2, u[j]); }
            float sum2 = 0.f;
#pragma unroll
            for (int j = 0; j < 6; ++j) sum2 += expf(u[j] - mx2);
            const float lse2 = mx2 + logf(sum2);
#pragma unroll
            for (int j = 0; j < 6; ++j) out[(size_t)NN * 7 + (size_t)gnode * 6 + j] = u[j] - lse2;
        }
    }
}

extern "C" void kernel_launch(void* const* d_in, const int* in_sizes, int n_in,
                              void* d_out, int out_size, void* d_ws, size_t ws_size,
                              hipStream_t stream) {
    const float* x   = (const float*)d_in[0];
    const int*   ei  = (const int*)d_in[1];
    const float* w_l = (const float*)d_in[2];
    const float* b_l = (const float*)d_in[3];
    const float* w_r = (const float*)d_in[4];
    const float* w_p = (const float*)d_in[5];
    const float* b_p = (const float*)d_in[6];
    const float* w_s = (const float*)d_in[7];
    const float* b_s = (const float*)d_in[8];
    float* out = (float*)d_out;

    float* agg = (float*)d_ws;                       // [NN*DIN] f32
    float* cnt = agg + (size_t)NN * DIN;             // [NN] f32

    hipMemsetAsync(d_ws, 0, ((size_t)NN * DIN + NN) * sizeof(float), stream);

    sage_scatter<<<(NE * 32) / 256, 256, 0, stream>>>(x, ei, agg, cnt);

    sage_gemm<<<(NN + 63) / 64, 256, 0, stream>>>(x, agg, cnt, w_l, b_l, w_r,
                                                  w_p, b_p, w_s, b_s, out);
}

// Round 2
// 636.086 us; speedup vs baseline: 2.5476x; 2.5476x over previous
//
#include <hip/hip_runtime.h>
#include <hip/hip_bf16.h>
#include <math.h>

#define NN 100000
#define NE 625000
#define DIN 128
#define DH 256

#define SCAN_BS 1024                      // elements per scan block
#define NB ((NN + SCAN_BS - 1) / SCAN_BS) // 98 scan blocks

// ---------------------------------------------------------------------------
// CSR build: histogram of dst
// ---------------------------------------------------------------------------
__global__ __launch_bounds__(256)
void sage_hist(const int* __restrict__ ei, int* __restrict__ deg) {
    int e = blockIdx.x * 256 + threadIdx.x;
    if (e >= NE) return;
    atomicAdd(&deg[ei[NE + e]], 1);
}

// ---------------------------------------------------------------------------
// Scan pass 1: per-block exclusive scan of deg (1024 elems / block of 256 thr)
// off[i] = block-local exclusive prefix; bsums[b] = block total.
// ---------------------------------------------------------------------------
__global__ __launch_bounds__(256)
void sage_scan1(const int* __restrict__ deg, int* __restrict__ off,
                int* __restrict__ bsums) {
    __shared__ int ss[256];
    const int t = threadIdx.x;
    const int base = blockIdx.x * SCAN_BS + t * 4;
    int v[4];
#pragma unroll
    for (int j = 0; j < 4; ++j) v[j] = (base + j < NN) ? deg[base + j] : 0;
    int tsum = v[0] + v[1] + v[2] + v[3];
    ss[t] = tsum;
    __syncthreads();
    for (int o = 1; o < 256; o <<= 1) {
        int u = (t >= o) ? ss[t - o] : 0;
        __syncthreads();
        ss[t] += u;
        __syncthreads();
    }
    int ex = ss[t] - tsum;                // exclusive prefix of thread sums
    int run = ex;
#pragma unroll
    for (int j = 0; j < 4; ++j) {
        if (base + j < NN) off[base + j] = run;
        run += v[j];
    }
    if (t == 255) bsums[blockIdx.x] = ss[255];
}

// ---------------------------------------------------------------------------
// Scan pass 2: single block, exclusive scan of the NB block sums in place.
// ---------------------------------------------------------------------------
__global__ __launch_bounds__(128)
void sage_scan2(int* __restrict__ bsums) {
    __shared__ int ss[128];
    const int t = threadIdx.x;
    int v = (t < NB) ? bsums[t] : 0;
    ss[t] = v;
    __syncthreads();
    for (int o = 1; o < 128; o <<= 1) {
        int u = (t >= o) ? ss[t - o] : 0;
        __syncthreads();
        ss[t] += u;
        __syncthreads();
    }
    if (t < NB) bsums[t] = ss[t] - v;     // exclusive
}

// ---------------------------------------------------------------------------
// Scan pass 3: add block offsets; also copy into cursor for the fill pass.
// ---------------------------------------------------------------------------
__global__ __launch_bounds__(256)
void sage_scan3(int* __restrict__ off, const int* __restrict__ bsums,
                int* __restrict__ cursor) {
    int i = blockIdx.x * 256 + threadIdx.x;
    if (i >= NN) return;
    int v = off[i] + bsums[i >> 10];
    off[i] = v;
    cursor[i] = v;
}

// ---------------------------------------------------------------------------
// CSR fill: elist[off[dst] + k] = src
// ---------------------------------------------------------------------------
__global__ __launch_bounds__(256)
void sage_fill(const int* __restrict__ ei, int* __restrict__ cursor,
               int* __restrict__ elist) {
    int e = blockIdx.x * 256 + threadIdx.x;
    if (e >= NE) return;
    int p = atomicAdd(&cursor[ei[NE + e]], 1);
    elist[p] = ei[e];
}

// ---------------------------------------------------------------------------
// Gather-aggregate: one wave per node, lane owns 2 floats of the 128-row.
// agg[n] = mean over in-neighbors of x[src]. No atomics, streaming write.
// ---------------------------------------------------------------------------
__global__ __launch_bounds__(256)
void sage_aggregate(const float* __restrict__ x, const int* __restrict__ elist,
                    const int* __restrict__ off, const int* __restrict__ deg,
                    float* __restrict__ agg) {
    int n = blockIdx.x * 4 + (threadIdx.x >> 6);
    if (n >= NN) return;
    int lane = threadIdx.x & 63;
    int start = off[n], d = deg[n];
    float2 s0 = {0.f, 0.f}, s1 = {0.f, 0.f};
    int i = 0;
    for (; i + 1 < d; i += 2) {
        int a = elist[start + i];
        int b = elist[start + i + 1];
        float2 va = *reinterpret_cast<const float2*>(x + (size_t)a * DIN + lane * 2);
        float2 vb = *reinterpret_cast<const float2*>(x + (size_t)b * DIN + lane * 2);
        s0.x += va.x; s0.y += va.y;
        s1.x += vb.x; s1.y += vb.y;
    }
    if (i < d) {
        int a = elist[start + i];
        float2 va = *reinterpret_cast<const float2*>(x + (size_t)a * DIN + lane * 2);
        s0.x += va.x; s0.y += va.y;
    }
    float invd = (d > 0) ? 1.f / (float)d : 0.f;
    float2 r;
    r.x = (s0.x + s1.x) * invd;
    r.y = (s0.y + s1.y) * invd;
    *reinterpret_cast<float2*>(agg + (size_t)n * DIN + lane * 2) = r;
}

// ---------------------------------------------------------------------------
// Fused GEMM + heads + log_softmax.  (unchanged from R1 except agg == mean)
// h = [mean | x] @ [w_l ; w_r] + b_l, relu  (K=256, N=256)
// ---------------------------------------------------------------------------
__global__ __launch_bounds__(256, 2)
void sage_gemm(const float* __restrict__ x,
               const float* __restrict__ agg,
               const float* __restrict__ w_l,
               const float* __restrict__ b_l,
               const float* __restrict__ w_r,
               const float* __restrict__ w_p,
               const float* __restrict__ b_p,
               const float* __restrict__ w_s,
               const float* __restrict__ b_s,
               float* __restrict__ out) {
    __shared__ float smem[17408];          // As(8K)+Ws(32K) / h tile (66560 B)
    __shared__ float out13[64][13];
    float* As = smem;                      // [32][64]  As[k][m]
    float* Ws = smem + 2048;               // [32][256] Ws[k][c]

    const int t = threadIdx.x;
    const int node0 = blockIdx.x * 64;

    float acc[16][4];
#pragma unroll
    for (int i = 0; i < 16; ++i)
#pragma unroll
        for (int j = 0; j < 4; ++j) acc[i][j] = 0.f;

    const int c0 = (t & 63) * 4;
    const int m0 = (t >> 6) * 16;

    const int node_l = t >> 2;
    const int kseg = (t & 3) * 8;
    const int gnode_s = node0 + node_l;
    const bool valid_s = gnode_s < NN;

    float av[8];
    float4 wv[8];

    auto loadA = [&](int kc, float a[8]) {
        const int kk = kc * 32 + kseg;
        if (valid_s) {
            const float* srcp = (kk < 128) ? (agg + (size_t)gnode_s * DIN + kk)
                                           : (x + (size_t)gnode_s * DIN + (kk - 128));
            float4 u0 = reinterpret_cast<const float4*>(srcp)[0];
            float4 u1 = reinterpret_cast<const float4*>(srcp)[1];
            a[0] = u0.x; a[1] = u0.y; a[2] = u0.z; a[3] = u0.w;
            a[4] = u1.x; a[5] = u1.y; a[6] = u1.z; a[7] = u1.w;
        } else {
#pragma unroll
            for (int j = 0; j < 8; ++j) a[j] = 0.f;
        }
    };
    auto loadW = [&](int kc, float4 w[8]) {
        const float* wsrc = (kc < 4) ? (w_l + (size_t)kc * 32 * 256)
                                     : (w_r + (size_t)(kc - 4) * 32 * 256);
#pragma unroll
        for (int j = 0; j < 8; ++j)
            w[j] = reinterpret_cast<const float4*>(wsrc)[t + j * 256];
    };

    loadA(0, av);
    loadW(0, wv);

    for (int kc = 0; kc < 8; ++kc) {
        __syncthreads();
#pragma unroll
        for (int j = 0; j < 8; ++j) As[(kseg + j) * 64 + node_l] = av[j];
#pragma unroll
        for (int j = 0; j < 8; ++j) reinterpret_cast<float4*>(Ws)[t + j * 256] = wv[j];
        __syncthreads();

        float avn[8];
        float4 wvn[8];
        if (kc < 7) { loadA(kc + 1, avn); loadW(kc + 1, wvn); }

#pragma unroll 4
        for (int k = 0; k < 32; ++k) {
            float4 w = *reinterpret_cast<const float4*>(Ws + k * 256 + c0);
            const float* ap = As + k * 64 + m0;
            float4 aa[4];
            aa[0] = reinterpret_cast<const float4*>(ap)[0];
            aa[1] = reinterpret_cast<const float4*>(ap)[1];
            aa[2] = reinterpret_cast<const float4*>(ap)[2];
            aa[3] = reinterpret_cast<const float4*>(ap)[3];
#pragma unroll
            for (int g = 0; g < 4; ++g) {
                float a4[4] = {aa[g].x, aa[g].y, aa[g].z, aa[g].w};
#pragma unroll
                for (int q = 0; q < 4; ++q) {
                    const int i = g * 4 + q;
                    acc[i][0] += a4[q] * w.x;
                    acc[i][1] += a4[q] * w.y;
                    acc[i][2] += a4[q] * w.z;
                    acc[i][3] += a4[q] * w.w;
                }
            }
        }

        if (kc < 7) {
#pragma unroll
            for (int j = 0; j < 8; ++j) { av[j] = avn[j]; wv[j] = wvn[j]; }
        }
    }

    __syncthreads();
    float4 bl = *reinterpret_cast<const float4*>(b_l + c0);
#pragma unroll
    for (int i = 0; i < 16; ++i) {
        float4 hv;
        hv.x = fmaxf(acc[i][0] + bl.x, 0.f);
        hv.y = fmaxf(acc[i][1] + bl.y, 0.f);
        hv.z = fmaxf(acc[i][2] + bl.z, 0.f);
        hv.w = fmaxf(acc[i][3] + bl.w, 0.f);
        *reinterpret_cast<float4*>(smem + (size_t)(m0 + i) * 260 + c0) = hv;
    }
    __syncthreads();

    for (int idx = t; idx < 832; idx += 256) {
        const int m = idx / 13;
        const int o = idx % 13;
        const float* hrow = smem + (size_t)m * 260;
        float s = 0.f;
        if (o < 7) {
            for (int k = 0; k < 256; k += 4) {
                float4 hv = *reinterpret_cast<const float4*>(hrow + k);
                s += hv.x * w_p[k * 7 + o] + hv.y * w_p[(k + 1) * 7 + o]
                   + hv.z * w_p[(k + 2) * 7 + o] + hv.w * w_p[(k + 3) * 7 + o];
            }
            s += b_p[o];
        } else {
            const int oo = o - 7;
            for (int k = 0; k < 256; k += 4) {
                float4 hv = *reinterpret_cast<const float4*>(hrow + k);
                s += hv.x * w_s[k * 6 + oo] + hv.y * w_s[(k + 1) * 6 + oo]
                   + hv.z * w_s[(k + 2) * 6 + oo] + hv.w * w_s[(k + 3) * 6 + oo];
            }
            s += b_s[oo];
        }
        out13[m][o] = s;
    }
    __syncthreads();

    if (t < 64) {
        const int gnode = node0 + t;
        if (gnode < NN) {
            float v[7], mx = -1e30f;
#pragma unroll
            for (int j = 0; j < 7; ++j) { v[j] = out13[t][j]; mx = fmaxf(mx, v[j]); }
            float sum = 0.f;
#pragma unroll
            for (int j = 0; j < 7; ++j) sum += expf(v[j] - mx);
            const float lse = mx + logf(sum);
#pragma unroll
            for (int j = 0; j < 7; ++j) out[(size_t)gnode * 7 + j] = v[j] - lse;

            float u[6], mx2 = -1e30f;
#pragma unroll
            for (int j = 0; j < 6; ++j) { u[j] = out13[t][7 + j]; mx2 = fmaxf(mx2, u[j]); }
            float sum2 = 0.f;
#pragma unroll
            for (int j = 0; j < 6; ++j) sum2 += expf(u[j] - mx2);
            const float lse2 = mx2 + logf(sum2);
#pragma unroll
            for (int j = 0; j < 6; ++j) out[(size_t)NN * 7 + (size_t)gnode * 6 + j] = u[j] - lse2;
        }
    }
}

extern "C" void kernel_launch(void* const* d_in, const int* in_sizes, int n_in,
                              void* d_out, int out_size, void* d_ws, size_t ws_size,
                              hipStream_t stream) {
    const float* x   = (const float*)d_in[0];
    const int*   ei  = (const int*)d_in[1];
    const float* w_l = (const float*)d_in[2];
    const float* b_l = (const float*)d_in[3];
    const float* w_r = (const float*)d_in[4];
    const float* w_p = (const float*)d_in[5];
    const float* b_p = (const float*)d_in[6];
    const float* w_s = (const float*)d_in[7];
    const float* b_s = (const float*)d_in[8];
    float* out = (float*)d_out;

    // workspace layout
    float* agg    = (float*)d_ws;                    // NN*DIN f32 (mean)
    int*   deg    = (int*)(agg + (size_t)NN * DIN);  // NN
    int*   off    = deg + NN;                        // NN
    int*   cursor = off + NN;                        // NN
    int*   bsums  = cursor + NN;                     // 128
    int*   elist  = bsums + 128;                     // NE

    hipMemsetAsync(deg, 0, NN * sizeof(int), stream);

    sage_hist<<<(NE + 255) / 256, 256, 0, stream>>>(ei, deg);
    sage_scan1<<<NB, 256, 0, stream>>>(deg, off, bsums);
    sage_scan2<<<1, 128, 0, stream>>>(bsums);
    sage_scan3<<<(NN + 255) / 256, 256, 0, stream>>>(off, bsums, cursor);
    sage_fill<<<(NE + 255) / 256, 256, 0, stream>>>(ei, cursor, elist);
    sage_aggregate<<<(NN + 3) / 4, 256, 0, stream>>>(x, elist, off, deg, agg);

    sage_gemm<<<(NN + 63) / 64, 256, 0, stream>>>(x, agg, w_l, b_l, w_r,
                                                  w_p, b_p, w_s, b_s, out);
}

// Round 3
// 368.307 us; speedup vs baseline: 4.3998x; 1.7271x over previous
//
#include <hip/hip_runtime.h>
#include <hip/hip_bf16.h>
#include <math.h>

#define NN 100000
#define NE 625000
#define DIN 128
#define DH 256
#define NROWS 100032                      // NN padded to 64

#define SCAN_BS 1024
#define NB ((NN + SCAN_BS - 1) / SCAN_BS) // 98 scan blocks

typedef __attribute__((ext_vector_type(8))) short bf16x8;
typedef __attribute__((ext_vector_type(4))) float f32x4;

__device__ __forceinline__ unsigned short f2bf(float f) {
    unsigned u = __builtin_bit_cast(unsigned, f);
    u += 0x7fffu + ((u >> 16) & 1u);      // RNE
    return (unsigned short)(u >> 16);
}
__device__ __forceinline__ float bf2f(unsigned short h) {
    unsigned u = ((unsigned)h) << 16;
    return __builtin_bit_cast(float, u);
}

// ---------------------------------------------------------------------------
// pack_w: w_cat[k][c] (k<128 -> w_l, else w_r) into MFMA B-fragment layout.
// Bp[((kt*16+ct)*64 + lane)*8 + j] = bf16(w_cat[kt*32+(lane>>4)*8+j][ct*16+(lane&15)])
// ---------------------------------------------------------------------------
__global__ __launch_bounds__(256)
void pack_w(const float* __restrict__ w_l, const float* __restrict__ w_r,
            unsigned short* __restrict__ Bp) {
    int tid = blockIdx.x * 256 + threadIdx.x;   // 8192 total
    int kt = tid >> 10;
    int ct = (tid >> 6) & 15;
    int L = tid & 63;
    int k0 = kt * 32 + (L >> 4) * 8;
    int c = ct * 16 + (L & 15);
    unsigned short v[8];
#pragma unroll
    for (int j = 0; j < 8; ++j) {
        int k = k0 + j;
        float w = (k < 128) ? w_l[k * 256 + c] : w_r[(k - 128) * 256 + c];
        v[j] = f2bf(w);
    }
    *reinterpret_cast<bf16x8*>(Bp + (size_t)tid * 8) =
        *reinterpret_cast<const bf16x8*>(v);
}

// ---------------------------------------------------------------------------
// xcast: A[n][128+j] = bf16(x[n][j])   (x-half of the fused A matrix)
// ---------------------------------------------------------------------------
__global__ __launch_bounds__(256)
void xcast(const float* __restrict__ x, unsigned short* __restrict__ A) {
    int idx = blockIdx.x * 256 + threadIdx.x;   // NN*32 threads
    if (idx >= NN * 32) return;
    int n = idx >> 5;
    int j4 = (idx & 31) * 4;
    float4 v = *reinterpret_cast<const float4*>(x + (size_t)n * DIN + j4);
    ushort4 o = { f2bf(v.x), f2bf(v.y), f2bf(v.z), f2bf(v.w) };
    *reinterpret_cast<ushort4*>(A + (size_t)n * 256 + 128 + j4) = o;
}

// ---------------------------------------------------------------------------
// CSR build
// ---------------------------------------------------------------------------
__global__ __launch_bounds__(256)
void sage_hist(const int* __restrict__ ei, int* __restrict__ deg) {
    int e = blockIdx.x * 256 + threadIdx.x;
    if (e >= NE) return;
    atomicAdd(&deg[ei[NE + e]], 1);
}

__global__ __launch_bounds__(256)
void sage_scan1(const int* __restrict__ deg, int* __restrict__ cursor,
                int* __restrict__ bsums) {
    __shared__ int ss[256];
    const int t = threadIdx.x;
    const int base = blockIdx.x * SCAN_BS + t * 4;
    int v[4];
#pragma unroll
    for (int j = 0; j < 4; ++j) v[j] = (base + j < NN) ? deg[base + j] : 0;
    int tsum = v[0] + v[1] + v[2] + v[3];
    ss[t] = tsum;
    __syncthreads();
    for (int o = 1; o < 256; o <<= 1) {
        int u = (t >= o) ? ss[t - o] : 0;
        __syncthreads();
        ss[t] += u;
        __syncthreads();
    }
    int run = ss[t] - tsum;
#pragma unroll
    for (int j = 0; j < 4; ++j) {
        if (base + j < NN) cursor[base + j] = run;
        run += v[j];
    }
    if (t == 255) bsums[blockIdx.x] = ss[255];
}

__global__ __launch_bounds__(128)
void sage_scan2(int* __restrict__ bsums) {
    __shared__ int ss[128];
    const int t = threadIdx.x;
    int v = (t < NB) ? bsums[t] : 0;
    ss[t] = v;
    __syncthreads();
    for (int o = 1; o < 128; o <<= 1) {
        int u = (t >= o) ? ss[t - o] : 0;
        __syncthreads();
        ss[t] += u;
        __syncthreads();
    }
    if (t < NB) bsums[t] = ss[t] - v;
}

__global__ __launch_bounds__(256)
void sage_scan3(int* __restrict__ cursor, const int* __restrict__ bsums) {
    int i = blockIdx.x * 256 + threadIdx.x;
    if (i >= NN) return;
    cursor[i] += bsums[i >> 10];
}

__global__ __launch_bounds__(256)
void sage_fill(const int* __restrict__ ei, int* __restrict__ cursor,
               int* __restrict__ elist) {
    int e = blockIdx.x * 256 + threadIdx.x;
    if (e >= NE) return;
    int p = atomicAdd(&cursor[ei[NE + e]], 1);
    elist[p] = ei[e];
}

// ---------------------------------------------------------------------------
// Gather-aggregate in bf16: one wave per node, lane owns 2 of 128 elems.
// Reads the x-half of A (bf16, 256 B/row), writes bf16 mean into A[n][0:128].
// After sage_fill, cursor[n] = off[n] + deg[n]  ->  start = cursor[n]-deg[n].
// ---------------------------------------------------------------------------
__global__ __launch_bounds__(256)
void sage_aggregate(unsigned short* __restrict__ A,
                    const int* __restrict__ elist,
                    const int* __restrict__ cursor,
                    const int* __restrict__ deg) {
    int n = blockIdx.x * 4 + (threadIdx.x >> 6);
    if (n >= NN) return;
    int lane = threadIdx.x & 63;
    int d = deg[n];
    int start = cursor[n] - d;
    float s0x = 0.f, s0y = 0.f, s1x = 0.f, s1y = 0.f;
    int i = 0;
    for (; i + 1 < d; i += 2) {
        int a = elist[start + i];
        int b = elist[start + i + 1];
        ushort2 va = *reinterpret_cast<const ushort2*>(A + (size_t)a * 256 + 128 + lane * 2);
        ushort2 vb = *reinterpret_cast<const ushort2*>(A + (size_t)b * 256 + 128 + lane * 2);
        s0x += bf2f(va.x); s0y += bf2f(va.y);
        s1x += bf2f(vb.x); s1y += bf2f(vb.y);
    }
    if (i < d) {
        int a = elist[start + i];
        ushort2 va = *reinterpret_cast<const ushort2*>(A + (size_t)a * 256 + 128 + lane * 2);
        s0x += bf2f(va.x); s0y += bf2f(va.y);
    }
    float invd = (d > 0) ? 1.f / (float)d : 0.f;
    ushort2 r = { f2bf((s0x + s1x) * invd), f2bf((s0y + s1y) * invd) };
    *reinterpret_cast<ushort2*>(A + (size_t)n * 256 + lane * 2) = r;
}

// ---------------------------------------------------------------------------
// MFMA GEMM: h[64 x 256] = A_tile[64 x 256] @ Bp + b_l, relu; heads; softmax.
// 4 waves/block; wave handles 16 rows x 256 cols = 16 MFMA tiles (16x16x32).
// Main loop is LDS-free: A frags direct from HBM, B frags from L1/L2.
// ---------------------------------------------------------------------------
__global__ __launch_bounds__(256)
void sage_gemm_mfma(const unsigned short* __restrict__ A,
                    const unsigned short* __restrict__ Bp,
                    const float* __restrict__ b_l,
                    const float* __restrict__ w_p,
                    const float* __restrict__ b_p,
                    const float* __restrict__ w_s,
                    const float* __restrict__ b_s,
                    float* __restrict__ out) {
    __shared__ float hs[64 * 260];         // h tile, stride 260 (bank-safe)
    __shared__ float out13[64][13];

    const int t = threadIdx.x;
    const int wave = t >> 6;
    const int L = t & 63;
    const int q = L >> 4;
    const int m15 = L & 15;
    const int node0 = blockIdx.x * 64;
    const int rowbase = node0 + wave * 16;

    // A fragments for this wave's 16 rows, all 8 k-tiles: 8 x dwordx4 per lane
    const unsigned short* arow = A + (size_t)(rowbase + m15) * 256;
    bf16x8 afrag[8];
#pragma unroll
    for (int kt = 0; kt < 8; ++kt)
        afrag[kt] = *reinterpret_cast<const bf16x8*>(arow + kt * 32 + q * 8);

    f32x4 acc[16];
#pragma unroll
    for (int ct = 0; ct < 16; ++ct) acc[ct] = (f32x4){0.f, 0.f, 0.f, 0.f};

#pragma unroll
    for (int kt = 0; kt < 8; ++kt) {
#pragma unroll
        for (int ct = 0; ct < 16; ++ct) {
            bf16x8 b = *reinterpret_cast<const bf16x8*>(
                Bp + ((size_t)(kt * 16 + ct) * 64 + L) * 8);
            acc[ct] = __builtin_amdgcn_mfma_f32_16x16x32_bf16(afrag[kt], b, acc[ct], 0, 0, 0);
        }
    }

    // epilogue: bias + relu -> LDS h tile
    // lane L holds D[row = wave*16 + q*4 + r][col = ct*16 + m15]
#pragma unroll
    for (int ct = 0; ct < 16; ++ct) {
        int c = ct * 16 + m15;
        float blv = b_l[c];
#pragma unroll
        for (int r = 0; r < 4; ++r) {
            int row = wave * 16 + q * 4 + r;
            hs[row * 260 + c] = fmaxf(acc[ct][r] + blv, 0.f);
        }
    }
    __syncthreads();

    // heads: 64 nodes x 13 outputs, f32
    for (int idx = t; idx < 832; idx += 256) {
        const int m = idx / 13;
        const int o = idx % 13;
        const float* hrow = hs + (size_t)m * 260;
        float s = 0.f;
        if (o < 7) {
            for (int k = 0; k < 256; k += 4) {
                float4 hv = *reinterpret_cast<const float4*>(hrow + k);
                s += hv.x * w_p[k * 7 + o] + hv.y * w_p[(k + 1) * 7 + o]
                   + hv.z * w_p[(k + 2) * 7 + o] + hv.w * w_p[(k + 3) * 7 + o];
            }
            s += b_p[o];
        } else {
            const int oo = o - 7;
            for (int k = 0; k < 256; k += 4) {
                float4 hv = *reinterpret_cast<const float4*>(hrow + k);
                s += hv.x * w_s[k * 6 + oo] + hv.y * w_s[(k + 1) * 6 + oo]
                   + hv.z * w_s[(k + 2) * 6 + oo] + hv.w * w_s[(k + 3) * 6 + oo];
            }
            s += b_s[oo];
        }
        out13[m][o] = s;
    }
    __syncthreads();

    // log_softmax + write
    if (t < 64) {
        const int gnode = node0 + t;
        if (gnode < NN) {
            float v[7], mx = -1e30f;
#pragma unroll
            for (int j = 0; j < 7; ++j) { v[j] = out13[t][j]; mx = fmaxf(mx, v[j]); }
            float sum = 0.f;
#pragma unroll
            for (int j = 0; j < 7; ++j) sum += expf(v[j] - mx);
            const float lse = mx + logf(sum);
#pragma unroll
            for (int j = 0; j < 7; ++j) out[(size_t)gnode * 7 + j] = v[j] - lse;

            float u[6], mx2 = -1e30f;
#pragma unroll
            for (int j = 0; j < 6; ++j) { u[j] = out13[t][7 + j]; mx2 = fmaxf(mx2, u[j]); }
            float sum2 = 0.f;
#pragma unroll
            for (int j = 0; j < 6; ++j) sum2 += expf(u[j] - mx2);
            const float lse2 = mx2 + logf(sum2);
#pragma unroll
            for (int j = 0; j < 6; ++j) out[(size_t)NN * 7 + (size_t)gnode * 6 + j] = u[j] - lse2;
        }
    }
}

extern "C" void kernel_launch(void* const* d_in, const int* in_sizes, int n_in,
                              void* d_out, int out_size, void* d_ws, size_t ws_size,
                              hipStream_t stream) {
    const float* x   = (const float*)d_in[0];
    const int*   ei  = (const int*)d_in[1];
    const float* w_l = (const float*)d_in[2];
    const float* b_l = (const float*)d_in[3];
    const float* w_r = (const float*)d_in[4];
    const float* w_p = (const float*)d_in[5];
    const float* b_p = (const float*)d_in[6];
    const float* w_s = (const float*)d_in[7];
    const float* b_s = (const float*)d_in[8];
    float* out = (float*)d_out;

    // workspace layout (54.65 MB)
    unsigned short* A  = (unsigned short*)d_ws;      // [NROWS][256] bf16: [mean|x]
    unsigned short* Bp = A + (size_t)NROWS * 256;    // [8*16*64*8] bf16 MFMA layout
    int* deg    = (int*)(Bp + 65536);                // NN
    int* cursor = deg + NN;                          // NN
    int* bsums  = cursor + NN;                       // 128
    int* elist  = bsums + 128;                       // NE

    hipMemsetAsync(deg, 0, NN * sizeof(int), stream);

    pack_w<<<32, 256, 0, stream>>>(w_l, w_r, Bp);
    xcast<<<(NN * 32 + 255) / 256, 256, 0, stream>>>(x, A);

    sage_hist<<<(NE + 255) / 256, 256, 0, stream>>>(ei, deg);
    sage_scan1<<<NB, 256, 0, stream>>>(deg, cursor, bsums);
    sage_scan2<<<1, 128, 0, stream>>>(bsums);
    sage_scan3<<<(NN + 255) / 256, 256, 0, stream>>>(cursor, bsums);
    sage_fill<<<(NE + 255) / 256, 256, 0, stream>>>(ei, cursor, elist);
    sage_aggregate<<<(NN + 3) / 4, 256, 0, stream>>>(A, elist, cursor, deg);

    sage_gemm_mfma<<<NROWS / 64, 256, 0, stream>>>(A, Bp, b_l, w_p, b_p, w_s, b_s, out);
}